// Round 1
// baseline (272.066 us; speedup 1.0000x reference)
//
#include <hip/hip_runtime.h>

#define LN2f 0.69314718055994530942f

typedef short s16x8 __attribute__((ext_vector_type(8)));
typedef float f32x4 __attribute__((ext_vector_type(4)));

constexpr int Bdim = 32, Ndim = 256, Kn = 64, Gdim = 64, Fdim = 128;
constexpr int TPB = 8;          // (b,n) tiles per block
constexpr int LDH = Fdim + 8;   // padded h row stride, bf16 elems (16B-aligned rows)

__device__ __forceinline__ short f2bf(float x) {
    // round-to-nearest-even f32 -> bf16 bit pattern
    unsigned u = __float_as_uint(x);
    u = (u + 0x7FFFu + ((u >> 16) & 1u)) >> 16;
    return (short)u;
}

__global__ __launch_bounds__(256, 2)
void cfconv_kernel(const float* __restrict__ features,
                   const float* __restrict__ rbf,
                   const int*   __restrict__ nbr,
                   const float* __restrict__ mask,
                   const float* __restrict__ W1,
                   const float* __restrict__ b1,
                   const float* __restrict__ W2,
                   const float* __restrict__ b2,
                   float* __restrict__ out)
{
    __shared__ short h_lds[Kn][LDH];      // 64 x 136 bf16 = 17408 B
    __shared__ int   nbr_lds[2][Kn];
    __shared__ float mask_lds[2][Kn];

    const int tid  = threadIdx.x;
    const int lane = tid & 63;
    const int w    = tid >> 6;      // wave 0..3 -> output col slab w*32
    const int l16  = lane & 15;
    const int grp  = lane >> 4;     // 0..3

    // ---- preload weight B-fragments into registers (once per block) ----
    // B-frag layout: col n = lane&15, k = 32*ks + 8*grp + j
    s16x8 w1f[2][2];
    #pragma unroll
    for (int ks = 0; ks < 2; ++ks)
      #pragma unroll
      for (int nf = 0; nf < 2; ++nf) {
        int g0 = ks*32 + grp*8;
        int f  = w*32 + nf*16 + l16;
        #pragma unroll
        for (int j = 0; j < 8; ++j)
          w1f[ks][nf][j] = f2bf(W1[(g0+j)*Fdim + f]);
      }
    s16x8 w2f[4][2];
    #pragma unroll
    for (int ks = 0; ks < 4; ++ks)
      #pragma unroll
      for (int nf = 0; nf < 2; ++nf) {
        int g0 = ks*32 + grp*8;
        int f  = w*32 + nf*16 + l16;
        #pragma unroll
        for (int j = 0; j < 8; ++j)
          w2f[ks][nf][j] = f2bf(W2[(g0+j)*Fdim + f]);
      }
    float b1v[2], b2v[2];
    #pragma unroll
    for (int nf = 0; nf < 2; ++nf) {
      int f = w*32 + nf*16 + l16;
      b1v[nf] = b1[f];
      b2v[nf] = b2[f];
    }

    for (int t = 0; t < TPB; ++t) {
        const int bn = blockIdx.x * TPB + t;
        const int b  = bn >> 8;     // N = 256

        // stage neighbor list & mask (double-buffered; read after sync2)
        if (tid < Kn) {
            nbr_lds[t & 1][tid]  = nbr[bn*Kn + tid];
            mask_lds[t & 1][tid] = mask[bn*Kn + tid];
        }

        // ---- GEMM1: pre = rbf @ W1 ; A-frags straight from global ----
        f32x4 acc[4][2];
        #pragma unroll
        for (int m = 0; m < 4; ++m)
          #pragma unroll
          for (int nf = 0; nf < 2; ++nf)
            acc[m][nf] = (f32x4){0.f, 0.f, 0.f, 0.f};

        const float* rb = rbf + (size_t)bn * (Kn * Gdim);
        #pragma unroll
        for (int m = 0; m < 4; ++m) {
          #pragma unroll
          for (int ks = 0; ks < 2; ++ks) {
            int row = m*16 + l16;           // A row = lane&15 (+16m)
            int g0  = ks*32 + grp*8;        // A k   = 8*grp + j (+32ks)
            const float4* p = (const float4*)(rb + row*Gdim + g0);
            float4 u = p[0], v = p[1];
            s16x8 a;
            a[0]=f2bf(u.x); a[1]=f2bf(u.y); a[2]=f2bf(u.z); a[3]=f2bf(u.w);
            a[4]=f2bf(v.x); a[5]=f2bf(v.y); a[6]=f2bf(v.z); a[7]=f2bf(v.w);
            #pragma unroll
            for (int nf = 0; nf < 2; ++nf)
              acc[m][nf] = __builtin_amdgcn_mfma_f32_16x16x32_bf16(
                               a, w1f[ks][nf], acc[m][nf], 0, 0, 0);
          }
        }

        // ---- shifted-softplus epilogue -> h_lds (C/D layout: row=4*grp+r, col=l16) ----
        #pragma unroll
        for (int m = 0; m < 4; ++m)
          #pragma unroll
          for (int nf = 0; nf < 2; ++nf)
            #pragma unroll
            for (int r = 0; r < 4; ++r) {
              float x  = acc[m][nf][r] + b1v[nf];
              float sp = fmaxf(x, 0.f) + __logf(1.f + __expf(-fabsf(x))) - LN2f;
              int row = m*16 + grp*4 + r;
              int col = w*32 + nf*16 + l16;
              h_lds[row][col] = f2bf(sp);
            }
        __syncthreads();

        // ---- GEMM2: filter = h @ W2 (A-frags via conflict-free ds_read_b128) ----
        #pragma unroll
        for (int m = 0; m < 4; ++m)
          #pragma unroll
          for (int nf = 0; nf < 2; ++nf)
            acc[m][nf] = (f32x4){0.f, 0.f, 0.f, 0.f};
        #pragma unroll
        for (int m = 0; m < 4; ++m) {
          #pragma unroll
          for (int ks = 0; ks < 4; ++ks) {
            const s16x8* ph = (const s16x8*)&h_lds[m*16 + l16][ks*32 + grp*8];
            s16x8 a = *ph;
            #pragma unroll
            for (int nf = 0; nf < 2; ++nf)
              acc[m][nf] = __builtin_amdgcn_mfma_f32_16x16x32_bf16(
                               a, w2f[ks][nf], acc[m][nf], 0, 0, 0);
          }
        }
        __syncthreads();

        // ---- gather neighbor features + masked sum over kn ----
        const float* fb = features + (size_t)b * (Ndim * Fdim);
        float o0 = 0.f, o1 = 0.f;
        #pragma unroll
        for (int m = 0; m < 4; ++m)
          #pragma unroll
          for (int r = 0; r < 4; ++r) {
            int   kn  = m*16 + grp*4 + r;        // filter row this lane holds
            int   idx = nbr_lds[t & 1][kn];
            float mk  = mask_lds[t & 1][kn];
            const float* fr = fb + idx * Fdim;
            int f0 = w*32 + l16;
            float flt0 = (acc[m][0][r] + b2v[0]) * mk;
            float flt1 = (acc[m][1][r] + b2v[1]) * mk;
            o0 += fr[f0]      * flt0;
            o1 += fr[f0 + 16] * flt1;
          }
        // reduce partial sums across the 4 lane-groups (rows are disjoint per group)
        o0 += __shfl_xor(o0, 16); o0 += __shfl_xor(o0, 32);
        o1 += __shfl_xor(o1, 16); o1 += __shfl_xor(o1, 32);
        float ov = (grp == 0) ? o0 : o1;
        if (grp < 2)
            out[(size_t)bn * Fdim + w*32 + grp*16 + l16] = ov;
    }
}

extern "C" void kernel_launch(void* const* d_in, const int* in_sizes, int n_in,
                              void* d_out, int out_size, void* d_ws, size_t ws_size,
                              hipStream_t stream) {
    const float* features = (const float*)d_in[0];
    const float* rbf      = (const float*)d_in[1];
    const int*   nbr      = (const int*)  d_in[2];
    const float* mask     = (const float*)d_in[3];
    const float* W1       = (const float*)d_in[4];
    const float* b1       = (const float*)d_in[5];
    const float* W2       = (const float*)d_in[6];
    const float* b2       = (const float*)d_in[7];
    float* out = (float*)d_out;

    dim3 grid(Bdim * Ndim / TPB), block(256);
    hipLaunchKernelGGL(cfconv_kernel, grid, block, 0, stream,
                       features, rbf, nbr, mask, W1, b1, W2, b2, out);
}

// Round 6
// 269.225 us; speedup vs baseline: 1.0106x; 1.0106x over previous
//
#include <hip/hip_runtime.h>

#define LN2f 0.69314718055994530942f

typedef short s16x8 __attribute__((ext_vector_type(8)));
typedef float f32x4 __attribute__((ext_vector_type(4)));

constexpr int Bdim = 32, Ndim = 256, Kn = 64, Gdim = 64, Fdim = 128;
constexpr int TPB = 8;          // (b,n) tiles per block -> grid 1024
constexpr int LDH = Fdim + 8;   // padded h row stride (bf16 elems)

__device__ __forceinline__ short f2bf(float x) {
    // round-to-nearest-even f32 -> bf16 bit pattern (R0-proven)
    unsigned u = __float_as_uint(x);
    u = (u + 0x7FFFu + ((u >> 16) & 1u)) >> 16;
    return (short)u;
}
__device__ __forceinline__ s16x8 cvt8(float4 u, float4 v) {
    s16x8 a;
    a[0]=f2bf(u.x); a[1]=f2bf(u.y); a[2]=f2bf(u.z); a[3]=f2bf(u.w);
    a[4]=f2bf(v.x); a[5]=f2bf(v.y); a[6]=f2bf(v.z); a[7]=f2bf(v.w);
    return a;
}

__global__ __launch_bounds__(256, 2)
void cfconv_kernel(const float* __restrict__ features,
                   const float* __restrict__ rbf,
                   const int*   __restrict__ nbr,
                   const float* __restrict__ mask,
                   const float* __restrict__ W1,
                   const float* __restrict__ b1,
                   const float* __restrict__ W2,
                   const float* __restrict__ b2,
                   float* __restrict__ out)
{
    __shared__ short h_lds[Kn][LDH];      // 64 x 136 bf16 = 17408 B (R0 layout)
    __shared__ int   nbr_lds[2][Kn];
    __shared__ float mask_lds[2][Kn];

    const int tid  = threadIdx.x;
    const int lane = tid & 63;
    const int w    = tid >> 6;      // wave -> output col slab w*32
    const int l16  = lane & 15;
    const int grp  = lane >> 4;     // 0..3

    // ---- weight B-fragments in registers (R0-proven mapping) ----
    // B-frag: col n = lane&15 -> f = w*32 + nf*16 + n ; k = 32*ks + 8*grp + j
    s16x8 w1f[2][2];
    #pragma unroll
    for (int ks = 0; ks < 2; ++ks)
      #pragma unroll
      for (int nf = 0; nf < 2; ++nf) {
        int g0 = ks*32 + grp*8;
        int f  = w*32 + nf*16 + l16;
        #pragma unroll
        for (int j = 0; j < 8; ++j)
          w1f[ks][nf][j] = f2bf(W1[(g0+j)*Fdim + f]);
      }
    s16x8 w2f[4][2];
    #pragma unroll
    for (int ks = 0; ks < 4; ++ks)
      #pragma unroll
      for (int nf = 0; nf < 2; ++nf) {
        int g0 = ks*32 + grp*8;
        int f  = w*32 + nf*16 + l16;
        #pragma unroll
        for (int j = 0; j < 8; ++j)
          w2f[ks][nf][j] = f2bf(W2[(g0+j)*Fdim + f]);
      }
    float b1v[2], b2v[2];
    #pragma unroll
    for (int nf = 0; nf < 2; ++nf) {
      int f = w*32 + nf*16 + l16;
      b1v[nf] = b1[f];
      b2v[nf] = b2[f];
    }

    const int bn0 = blockIdx.x * TPB;

    // ---- prologue: batch-issue ALL 16 rbf dwordx4 loads for tile 0 ----
    float4 st[8][2];                 // i = m*2 + ks
    {
        const float* rb = rbf + (size_t)bn0 * (Kn * Gdim) + l16 * Gdim + grp * 8;
        #pragma unroll
        for (int i = 0; i < 8; ++i) {
            const float* p = rb + (i >> 1) * 16 * Gdim + (i & 1) * 32;
            st[i][0] = *(const float4*)p;
            st[i][1] = *(const float4*)(p + 4);
        }
    }

    for (int t = 0; t < TPB; ++t) {
        const int bn = bn0 + t;
        const int b  = bn >> 8;      // N = 256

        // stage neighbor list & mask (double-buffered; read after 2nd barrier)
        if (tid < Kn) {
            nbr_lds[t & 1][tid]  = nbr[bn*Kn + tid];
            mask_lds[t & 1][tid] = mask[bn*Kn + tid];
        }

        // ---- consume st -> A-fragments, then immediately prefetch tile t+1 ----
        s16x8 af[4][2];
        #pragma unroll
        for (int m = 0; m < 4; ++m) {
            af[m][0] = cvt8(st[m*2][0],   st[m*2][1]);
            af[m][1] = cvt8(st[m*2+1][0], st[m*2+1][1]);
        }
        if (t + 1 < TPB) {
            const float* rbn = rbf + (size_t)(bn + 1) * (Kn * Gdim) + l16 * Gdim + grp * 8;
            #pragma unroll
            for (int i = 0; i < 8; ++i) {
                const float* p = rbn + (i >> 1) * 16 * Gdim + (i & 1) * 32;
                st[i][0] = *(const float4*)p;
                st[i][1] = *(const float4*)(p + 4);
            }
        }

        // ---- GEMM1: pre = rbf @ W1 ----
        f32x4 acc[4][2];
        #pragma unroll
        for (int m = 0; m < 4; ++m)
          #pragma unroll
          for (int nf = 0; nf < 2; ++nf)
            acc[m][nf] = (f32x4){0.f, 0.f, 0.f, 0.f};
        #pragma unroll
        for (int m = 0; m < 4; ++m)
          #pragma unroll
          for (int ks = 0; ks < 2; ++ks)
            #pragma unroll
            for (int nf = 0; nf < 2; ++nf)
              acc[m][nf] = __builtin_amdgcn_mfma_f32_16x16x32_bf16(
                               af[m][ks], w1f[ks][nf], acc[m][nf], 0, 0, 0);

        // ---- shifted-softplus epilogue -> h_lds (C/D: row=m*16+grp*4+r, col=l16) ----
        #pragma unroll
        for (int m = 0; m < 4; ++m)
          #pragma unroll
          for (int nf = 0; nf < 2; ++nf)
            #pragma unroll
            for (int r = 0; r < 4; ++r) {
              float x  = acc[m][nf][r] + b1v[nf];
              float sp = fmaxf(x, 0.f) + __logf(1.f + __expf(-fabsf(x))) - LN2f;
              int row = m*16 + grp*4 + r;
              int col = w*32 + nf*16 + l16;
              h_lds[row][col] = f2bf(sp);
            }
        __syncthreads();

        // ---- GEMM2: filter = h @ W2 ----
        #pragma unroll
        for (int m = 0; m < 4; ++m)
          #pragma unroll
          for (int nf = 0; nf < 2; ++nf)
            acc[m][nf] = (f32x4){0.f, 0.f, 0.f, 0.f};
        #pragma unroll
        for (int m = 0; m < 4; ++m) {
          #pragma unroll
          for (int ks = 0; ks < 4; ++ks) {
            s16x8 a = *(const s16x8*)&h_lds[m*16 + l16][ks*32 + grp*8];
            #pragma unroll
            for (int nf = 0; nf < 2; ++nf)
              acc[m][nf] = __builtin_amdgcn_mfma_f32_16x16x32_bf16(
                               a, w2f[ks][nf], acc[m][nf], 0, 0, 0);
          }
        }
        __syncthreads();

        // ---- gather neighbor features + masked sum over kn (R0-exact) ----
        const float* fb = features + (size_t)b * (Ndim * Fdim);
        float o0 = 0.f, o1 = 0.f;
        #pragma unroll
        for (int m = 0; m < 4; ++m)
          #pragma unroll
          for (int r = 0; r < 4; ++r) {
            int   kn  = m*16 + grp*4 + r;        // filter row this lane holds
            int   idx = nbr_lds[t & 1][kn];
            float mk  = mask_lds[t & 1][kn];
            const float* fr = fb + idx * Fdim;
            int f0 = w*32 + l16;
            float flt0 = (acc[m][0][r] + b2v[0]) * mk;
            float flt1 = (acc[m][1][r] + b2v[1]) * mk;
            o0 += fr[f0]      * flt0;
            o1 += fr[f0 + 16] * flt1;
          }
        // reduce partial sums across the 4 lane-groups (rows disjoint per group)
        o0 += __shfl_xor(o0, 16); o0 += __shfl_xor(o0, 32);
        o1 += __shfl_xor(o1, 16); o1 += __shfl_xor(o1, 32);
        float ov = (grp == 0) ? o0 : o1;
        if (grp < 2)
            out[(size_t)bn * Fdim + w*32 + grp*16 + l16] = ov;
    }
}

extern "C" void kernel_launch(void* const* d_in, const int* in_sizes, int n_in,
                              void* d_out, int out_size, void* d_ws, size_t ws_size,
                              hipStream_t stream) {
    const float* features = (const float*)d_in[0];
    const float* rbf      = (const float*)d_in[1];
    const int*   nbr      = (const int*)  d_in[2];
    const float* mask     = (const float*)d_in[3];
    const float* W1       = (const float*)d_in[4];
    const float* b1       = (const float*)d_in[5];
    const float* W2       = (const float*)d_in[6];
    const float* b2       = (const float*)d_in[7];
    float* out = (float*)d_out;

    dim3 grid(Bdim * Ndim / TPB), block(256);
    hipLaunchKernelGGL(cfconv_kernel, grid, block, 0, stream,
                       features, rbf, nbr, mask, W1, b1, W2, b2, out);
}

// Round 7
// 261.513 us; speedup vs baseline: 1.0404x; 1.0295x over previous
//
#include <hip/hip_runtime.h>

#define LN2f 0.69314718055994530942f

typedef short s16x8 __attribute__((ext_vector_type(8)));
typedef float f32x4 __attribute__((ext_vector_type(4)));
typedef unsigned int u32;
typedef unsigned int u32x4 __attribute__((ext_vector_type(4)));

constexpr int Bdim = 32, Ndim = 256, Kn = 64, Gdim = 64, Fdim = 128;
constexpr int TPB = 8;          // (b,n) tiles per block -> grid 1024
constexpr int LDH = Fdim + 8;   // padded h row stride (bf16 elems)

// packed f32x2 -> bf16x2 (register-only inline asm; 1 inst per 2 elems)
__device__ __forceinline__ u32 cvtpk(float lo, float hi) {
    u32 r;
    asm("v_cvt_pk_bf16_f32 %0, %1, %2" : "=v"(r) : "v"(lo), "v"(hi));
    return r;
}
__device__ __forceinline__ s16x8 cvt8(float4 u, float4 v) {
    u32x4 q = { cvtpk(u.x, u.y), cvtpk(u.z, u.w), cvtpk(v.x, v.y), cvtpk(v.z, v.w) };
    return __builtin_bit_cast(s16x8, q);
}

__global__ __launch_bounds__(256, 2)
void cfconv_kernel(const float* __restrict__ features,
                   const float* __restrict__ rbf,
                   const int*   __restrict__ nbr,
                   const float* __restrict__ mask,
                   const float* __restrict__ W1,
                   const float* __restrict__ b1,
                   const float* __restrict__ W2,
                   const float* __restrict__ b2,
                   float* __restrict__ out)
{
    __shared__ short h_lds[Kn][LDH];      // 64 x 136 bf16 (R0-proven layout)
    __shared__ int   nbr_lds[2][Kn];
    __shared__ float mask_lds[2][Kn];

    const int tid  = threadIdx.x;
    const int lane = tid & 63;
    const int w    = tid >> 6;      // wave -> output col slab w*32
    const int l16  = lane & 15;
    const int grp  = lane >> 4;     // 0..3
    const int f0   = w * 32 + l16;  // this lane's nf=0 column; nf=1 is f0+16

    // ---- weight B-fragments in registers (R0-proven mapping, cvt_pk packed) ----
    // B-frag: col n = lane&15 -> f = w*32 + nf*16 + n ; k = 32*ks + 8*grp + j
    s16x8 w1f[2][2];
    #pragma unroll
    for (int ks = 0; ks < 2; ++ks)
      #pragma unroll
      for (int nf = 0; nf < 2; ++nf) {
        int g0 = ks*32 + grp*8;
        int f  = w*32 + nf*16 + l16;
        u32x4 q;
        #pragma unroll
        for (int j2 = 0; j2 < 4; ++j2)
          q[j2] = cvtpk(W1[(g0 + 2*j2)*Fdim + f], W1[(g0 + 2*j2 + 1)*Fdim + f]);
        w1f[ks][nf] = __builtin_bit_cast(s16x8, q);
      }
    s16x8 w2f[4][2];
    #pragma unroll
    for (int ks = 0; ks < 4; ++ks)
      #pragma unroll
      for (int nf = 0; nf < 2; ++nf) {
        int g0 = ks*32 + grp*8;
        int f  = w*32 + nf*16 + l16;
        u32x4 q;
        #pragma unroll
        for (int j2 = 0; j2 < 4; ++j2)
          q[j2] = cvtpk(W2[(g0 + 2*j2)*Fdim + f], W2[(g0 + 2*j2 + 1)*Fdim + f]);
        w2f[ks][nf] = __builtin_bit_cast(s16x8, q);
      }
    float b1v[2], b2v[2];
    #pragma unroll
    for (int nf = 0; nf < 2; ++nf) {
      int f = w*32 + nf*16 + l16;
      b1v[nf] = b1[f];
      b2v[nf] = b2[f];
    }

    const int bn0 = blockIdx.x * TPB;

    // ---- prologue: batch-issue ALL 16 rbf dwordx4 loads for tile 0 ----
    float4 st[8][2];                 // i = m*2 + ks
    {
        const float* rb = rbf + (size_t)bn0 * (Kn * Gdim) + l16 * Gdim + grp * 8;
        #pragma unroll
        for (int i = 0; i < 8; ++i) {
            const float* p = rb + (i >> 1) * 16 * Gdim + (i & 1) * 32;
            st[i][0] = *(const float4*)p;
            st[i][1] = *(const float4*)(p + 4);
        }
    }

    for (int t = 0; t < TPB; ++t) {
        const int bn = bn0 + t;
        const int b  = bn >> 8;      // N = 256
        const int cb = t & 1;

        // stage neighbor list & mask (double-buffered; read after barrier 1)
        if (tid < Kn) {
            nbr_lds[cb][tid]  = nbr[bn*Kn + tid];
            mask_lds[cb][tid] = mask[bn*Kn + tid];
        }

        // ---- consume st -> A-fragments, then immediately prefetch tile t+1 ----
        s16x8 af[4][2];
        #pragma unroll
        for (int m = 0; m < 4; ++m) {
            af[m][0] = cvt8(st[m*2][0],   st[m*2][1]);
            af[m][1] = cvt8(st[m*2+1][0], st[m*2+1][1]);
        }
        if (t + 1 < TPB) {
            const float* rbn = rbf + (size_t)(bn + 1) * (Kn * Gdim) + l16 * Gdim + grp * 8;
            #pragma unroll
            for (int i = 0; i < 8; ++i) {
                const float* p = rbn + (i >> 1) * 16 * Gdim + (i & 1) * 32;
                st[i][0] = *(const float4*)p;
                st[i][1] = *(const float4*)(p + 4);
            }
        }

        // ---- GEMM1: pre = rbf @ W1 ----
        f32x4 acc[4][2];
        #pragma unroll
        for (int m = 0; m < 4; ++m)
          #pragma unroll
          for (int nf = 0; nf < 2; ++nf)
            acc[m][nf] = (f32x4){0.f, 0.f, 0.f, 0.f};
        #pragma unroll
        for (int m = 0; m < 4; ++m)
          #pragma unroll
          for (int ks = 0; ks < 2; ++ks)
            #pragma unroll
            for (int nf = 0; nf < 2; ++nf)
              acc[m][nf] = __builtin_amdgcn_mfma_f32_16x16x32_bf16(
                               af[m][ks], w1f[ks][nf], acc[m][nf], 0, 0, 0);

        // ---- shifted-softplus epilogue -> h_lds (C/D: row=m*16+grp*4+r, col=l16) ----
        #pragma unroll
        for (int m = 0; m < 4; ++m)
          #pragma unroll
          for (int r = 0; r < 4; ++r) {
            float x0 = acc[m][0][r] + b1v[0];
            float x1 = acc[m][1][r] + b1v[1];
            float s0 = fmaxf(x0, 0.f) + __logf(1.f + __expf(-fabsf(x0))) - LN2f;
            float s1 = fmaxf(x1, 0.f) + __logf(1.f + __expf(-fabsf(x1))) - LN2f;
            u32 p = cvtpk(s0, s1);
            int row = m*16 + grp*4 + r;
            h_lds[row][f0]      = (short)(p & 0xffffu);
            h_lds[row][f0 + 16] = (short)(p >> 16);
          }
        __syncthreads();   // B1: h_lds ready for all waves

        const float* fb = features + (size_t)b * (Ndim * Fdim);

        // ---- batch A: issue gathers for rows m=0,1 (idx from LDS, then 16 loads) ----
        float fa0[8], fa1[8];
        #pragma unroll
        for (int i = 0; i < 8; ++i) {
            int kn  = (i >> 2)*16 + grp*4 + (i & 3);      // m = i>>2 (0,1)
            const float* fr = fb + (size_t)nbr_lds[cb][kn] * Fdim;
            fa0[i] = fr[f0];
            fa1[i] = fr[f0 + 16];
        }

        // ---- GEMM2 rows m=0,1 ----
        f32x4 c2[2][2];
        #pragma unroll
        for (int m = 0; m < 2; ++m) {
          c2[m][0] = (f32x4){0.f,0.f,0.f,0.f};
          c2[m][1] = (f32x4){0.f,0.f,0.f,0.f};
          #pragma unroll
          for (int ks = 0; ks < 4; ++ks) {
            s16x8 a = *(const s16x8*)&h_lds[m*16 + l16][ks*32 + grp*8];
            c2[m][0] = __builtin_amdgcn_mfma_f32_16x16x32_bf16(a, w2f[ks][0], c2[m][0], 0,0,0);
            c2[m][1] = __builtin_amdgcn_mfma_f32_16x16x32_bf16(a, w2f[ks][1], c2[m][1], 0,0,0);
          }
        }

        // ---- batch B: issue gathers for rows m=2,3 ----
        float fb0[8], fb1[8];
        #pragma unroll
        for (int i = 0; i < 8; ++i) {
            int kn  = (2 + (i >> 2))*16 + grp*4 + (i & 3);
            const float* fr = fb + (size_t)nbr_lds[cb][kn] * Fdim;
            fb0[i] = fr[f0];
            fb1[i] = fr[f0 + 16];
        }

        // ---- accumulate m=0,1 (independent partials to break FMA chain) ----
        float o0 = 0.f, o1 = 0.f, p0 = 0.f, p1 = 0.f;
        #pragma unroll
        for (int i = 0; i < 8; ++i) {
            int m = i >> 2, r = i & 3;
            int kn = m*16 + grp*4 + r;
            float mk = mask_lds[cb][kn];
            if (i & 1) { p0 += fa0[i] * ((c2[m][0][r] + b2v[0]) * mk);
                         p1 += fa1[i] * ((c2[m][1][r] + b2v[1]) * mk); }
            else       { o0 += fa0[i] * ((c2[m][0][r] + b2v[0]) * mk);
                         o1 += fa1[i] * ((c2[m][1][r] + b2v[1]) * mk); }
        }

        // ---- GEMM2 rows m=2,3 (reuse c2) ----
        #pragma unroll
        for (int m = 0; m < 2; ++m) {
          c2[m][0] = (f32x4){0.f,0.f,0.f,0.f};
          c2[m][1] = (f32x4){0.f,0.f,0.f,0.f};
          #pragma unroll
          for (int ks = 0; ks < 4; ++ks) {
            s16x8 a = *(const s16x8*)&h_lds[(m+2)*16 + l16][ks*32 + grp*8];
            c2[m][0] = __builtin_amdgcn_mfma_f32_16x16x32_bf16(a, w2f[ks][0], c2[m][0], 0,0,0);
            c2[m][1] = __builtin_amdgcn_mfma_f32_16x16x32_bf16(a, w2f[ks][1], c2[m][1], 0,0,0);
          }
        }

        // ---- accumulate m=2,3 ----
        #pragma unroll
        for (int i = 0; i < 8; ++i) {
            int m = i >> 2, r = i & 3;
            int kn = (m+2)*16 + grp*4 + r;
            float mk = mask_lds[cb][kn];
            if (i & 1) { p0 += fb0[i] * ((c2[m][0][r] + b2v[0]) * mk);
                         p1 += fb1[i] * ((c2[m][1][r] + b2v[1]) * mk); }
            else       { o0 += fb0[i] * ((c2[m][0][r] + b2v[0]) * mk);
                         o1 += fb1[i] * ((c2[m][1][r] + b2v[1]) * mk); }
        }
        o0 += p0; o1 += p1;

        // ---- reduce across the 4 lane-groups (rows disjoint per group) ----
        o0 += __shfl_xor(o0, 16); o0 += __shfl_xor(o0, 32);
        o1 += __shfl_xor(o1, 16); o1 += __shfl_xor(o1, 32);
        float ov = (grp == 0) ? o0 : o1;
        if (grp < 2)
            out[(size_t)bn * Fdim + w*32 + grp*16 + l16] = ov;

        __syncthreads();   // B2: h_lds WAR protection for next tile's epilogue
    }
}

extern "C" void kernel_launch(void* const* d_in, const int* in_sizes, int n_in,
                              void* d_out, int out_size, void* d_ws, size_t ws_size,
                              hipStream_t stream) {
    const float* features = (const float*)d_in[0];
    const float* rbf      = (const float*)d_in[1];
    const int*   nbr      = (const int*)  d_in[2];
    const float* mask     = (const float*)d_in[3];
    const float* W1       = (const float*)d_in[4];
    const float* b1       = (const float*)d_in[5];
    const float* W2       = (const float*)d_in[6];
    const float* b2       = (const float*)d_in[7];
    float* out = (float*)d_out;

    dim3 grid(Bdim * Ndim / TPB), block(256);
    hipLaunchKernelGGL(cfconv_kernel, grid, block, 0, stream,
                       features, rbf, nbr, mask, W1, b1, W2, b2, out);
}